// Round 1
// baseline (494.564 us; speedup 1.0000x reference)
//
#include <hip/hip_runtime.h>

// ---------------------------------------------------------------------------
// MHA: out = softmax_causal((xWq)(xWk)^T / sqrt(64)) (xWv) Wo
// B=4 T=2048 D=1024 H=16 Dh=64.  All matmuls in bf16 MFMA (fp32 accum).
// ---------------------------------------------------------------------------

typedef short  short8  __attribute__((ext_vector_type(8)));
typedef short  short4v __attribute__((ext_vector_type(4)));
typedef float  floatx4 __attribute__((ext_vector_type(4)));

#define T_SZ 2048
#define DM   1024

__device__ __forceinline__ short f2bf(float f) {
  unsigned u = __float_as_uint(f);
  u += 0x7fffu + ((u >> 16) & 1u);        // RNE
  return (short)(u >> 16);
}

__device__ __forceinline__ void gll16(const void* g, void* l) {
  // async global->LDS, 16B/lane, dest = wave-uniform base + lane*16
  __builtin_amdgcn_global_load_lds((const __attribute__((address_space(1))) void*)g,
                                   (__attribute__((address_space(3))) void*)l, 16, 0, 0);
}

// -------------------------------------------------- x fp32 -> bf16
__global__ void cvt_x_kernel(const float* __restrict__ x, short* __restrict__ xb) {
  const int i = (blockIdx.x * 256 + threadIdx.x) * 4;
  const float4 v = *(const float4*)(x + i);
  short4v o;
  o.x = f2bf(v.x); o.y = f2bf(v.y); o.z = f2bf(v.z); o.w = f2bf(v.w);
  *(short4v*)(xb + i) = o;
}

// -------------------------------------------------- W fp32 [K,N] -> bf16 W^T [N,K]
__global__ void cvt_w_kernel(const float* __restrict__ s0, const float* __restrict__ s1,
                             const float* __restrict__ s2, const float* __restrict__ s3,
                             short* __restrict__ dst) {
  const float* srcs[4] = {s0, s1, s2, s3};
  const float* src = srcs[blockIdx.z];
  short* d = dst + (size_t)blockIdx.z * 1048576;
  __shared__ float tile[32][33];
  const int tx = threadIdx.x, ty = threadIdx.y;       // block (32,8)
  const int n_base = blockIdx.x * 32, k_base = blockIdx.y * 32;
#pragma unroll
  for (int j = 0; j < 4; ++j)
    tile[ty + j * 8][tx] = src[(size_t)(k_base + ty + j * 8) * 1024 + n_base + tx];
  __syncthreads();
#pragma unroll
  for (int j = 0; j < 4; ++j)
    d[(size_t)(n_base + ty + j * 8) * 1024 + k_base + tx] = f2bf(tile[tx][ty + j * 8]);
}

// -------------------------------------------------- GEMM  C = A[M,K] * Bt[N,K]^T
// m97 structure: 128x128 tile, BK=32, 256 thr (4 waves), wave = 64x64 (4x4 mfma tiles)
// MODE 0: QKV epilogue -> bf16 [3][B*H][T][64], scale 0.125 on weight 0
// MODE 1: fp32 row-major epilogue -> d_out
template <int MODE>
__global__ void gemm_bt(const short* __restrict__ A, const short* __restrict__ Bt,
                        short* __restrict__ obf, float* __restrict__ of, int K) {
  __shared__ short As[128 * 32];
  __shared__ short Bs[128 * 32];
  const int tid  = threadIdx.x;
  const int w    = tid >> 6, lane = tid & 63;
  const int quad = lane >> 4, l15 = lane & 15;
  const int wr   = w >> 1, wc = w & 1;
  const int m0   = blockIdx.x * 128;
  const int n0   = blockIdx.y * 128;
  const int arow = tid >> 2, apart = tid & 3;

  floatx4 acc[4][4] = {};

  for (int kk = 0; kk < K; kk += 32) {
    gll16(A  + (size_t)(m0 + arow) * K      + kk + apart * 8, &As[tid * 8]);
    gll16(A  + (size_t)(m0 + 64 + arow) * K + kk + apart * 8, &As[(256 + tid) * 8]);
    gll16(Bt + (size_t)(n0 + arow) * K      + kk + apart * 8, &Bs[tid * 8]);
    gll16(Bt + (size_t)(n0 + 64 + arow) * K + kk + apart * 8, &Bs[(256 + tid) * 8]);
    __syncthreads();
    short8 af[4], bf[4];
#pragma unroll
    for (int i = 0; i < 4; ++i)
      af[i] = *(const short8*)&As[(wr * 64 + i * 16 + l15) * 32 + quad * 8];
#pragma unroll
    for (int j = 0; j < 4; ++j)
      bf[j] = *(const short8*)&Bs[(wc * 64 + j * 16 + l15) * 32 + quad * 8];
#pragma unroll
    for (int i = 0; i < 4; ++i)
#pragma unroll
      for (int j = 0; j < 4; ++j)
        acc[i][j] = __builtin_amdgcn_mfma_f32_16x16x32_bf16(af[i], bf[j], acc[i][j], 0, 0, 0);
    __syncthreads();
  }

  if (MODE == 0) {
    const int wsel = n0 >> 10;
    const float scale = (wsel == 0) ? 0.125f : 1.0f;   // fold Dh^-0.5 into Q
    short* outw = obf + (size_t)wsel * (64u * 2048u * 64u);
    const int ncol0 = (n0 & 1023) + wc * 64;
#pragma unroll
    for (int i = 0; i < 4; ++i) {
      const int row0 = m0 + wr * 64 + i * 16 + quad * 4;
#pragma unroll
      for (int j = 0; j < 4; ++j) {
        const int col = ncol0 + j * 16 + l15;
        const int h = col >> 6, d = col & 63;
#pragma unroll
        for (int r = 0; r < 4; ++r) {
          const int rg = row0 + r;
          const int b = rg >> 11, t = rg & 2047;
          outw[(((size_t)(b * 16 + h) * 2048 + t) << 6) + d] = f2bf(acc[i][j][r] * scale);
        }
      }
    }
  } else {
#pragma unroll
    for (int i = 0; i < 4; ++i) {
      const int row0 = m0 + wr * 64 + i * 16 + quad * 4;
#pragma unroll
      for (int j = 0; j < 4; ++j) {
        const int col = n0 + wc * 64 + j * 16 + l15;
#pragma unroll
        for (int r = 0; r < 4; ++r)
          of[(size_t)(row0 + r) * 1024 + col] = acc[i][j][r];
      }
    }
  }
}

// -------------------------------------------------- flash attention (causal)
// grid (T/64, B*H), block 256.  Wave w owns q rows [q0+16w, q0+16w+16).
// Q pre-scaled by 0.125 at projection.  Q/K/V layout [B*H][T][64] bf16.
__global__ void attn_kernel(const short* __restrict__ Qg, const short* __restrict__ Kg,
                            const short* __restrict__ Vg, short* __restrict__ ctx) {
  __shared__ short Ks[64 * 72];        // [kk][d], stride 72 breaks bank conflicts
  __shared__ short Vs[64 * 72];        // transposed: [d][kk]
  __shared__ short Ps[4][16 * 72];     // per-wave P (C-layout -> A-layout round trip)

  const int tid  = threadIdx.x;
  const int w    = tid >> 6, lane = tid & 63;
  const int quad = lane >> 4, l15 = lane & 15;
  const int bh = blockIdx.y;
  const int b  = bh >> 4, h = bh & 15;
  const int q0 = blockIdx.x * 64;

  const size_t base = (size_t)bh * (T_SZ * 64);
  const short* Qb = Qg + base;
  const short* Kb = Kg + base;
  const short* Vb = Vg + base;

  short8 qf0, qf1;
  {
    const int qrow = q0 + w * 16 + l15;           // A-frag: m = lane&15
    qf0 = *(const short8*)(Qb + qrow * 64 + quad * 8);
    qf1 = *(const short8*)(Qb + qrow * 64 + 32 + quad * 8);
  }

  floatx4 O[4] = {};
  float m_i[4], l_i[4];
#pragma unroll
  for (int r = 0; r < 4; ++r) { m_i[r] = -1e30f; l_i[r] = 0.0f; }

  const int rowbase = q0 + w * 16;
  const int ktiles = (q0 >> 6) + 1;               // causal: k0 <= q0

  for (int kt = 0; kt < ktiles; ++kt) {
    const int k0 = kt * 64;
    // stage K, and V transposed (8KB each)
#pragma unroll
    for (int e = 0; e < 2; ++e) {
      const int s = e * 256 + tid;
      const int row = s >> 3, part = s & 7;
      *(short8*)(&Ks[row * 72 + part * 8]) =
          *(const short8*)(Kb + (k0 + row) * 64 + part * 8);
      short8 vv = *(const short8*)(Vb + (k0 + row) * 64 + part * 8);
#pragma unroll
      for (int j = 0; j < 8; ++j) Vs[(part * 8 + j) * 72 + row] = vv[j];
    }
    __syncthreads();

    const bool active = (k0 <= rowbase + 15);     // else tile fully masked for this wave
    if (active) {
      floatx4 s4[4] = {};
#pragma unroll
      for (int nt = 0; nt < 4; ++nt) {
        short8 kf0 = *(const short8*)(&Ks[(nt * 16 + l15) * 72 + quad * 8]);
        short8 kf1 = *(const short8*)(&Ks[(nt * 16 + l15) * 72 + 32 + quad * 8]);
        s4[nt] = __builtin_amdgcn_mfma_f32_16x16x32_bf16(qf0, kf0, s4[nt], 0, 0, 0);
        s4[nt] = __builtin_amdgcn_mfma_f32_16x16x32_bf16(qf1, kf1, s4[nt], 0, 0, 0);
      }
      if (k0 + 63 > rowbase) {                    // diagonal tile: element mask
#pragma unroll
        for (int nt = 0; nt < 4; ++nt) {
          const int col = k0 + nt * 16 + l15;
#pragma unroll
          for (int r = 0; r < 4; ++r)
            if (col > rowbase + quad * 4 + r) s4[nt][r] = -1e30f;
        }
      }
      // online softmax; row r of this 16-row strip lives in quad = r>>2, reg = r&3,
      // replicated across the quad's 16 lanes after the shuffle reduce.
      float mnew[4], alpha[4], rs[4];
#pragma unroll
      for (int r = 0; r < 4; ++r)
        mnew[r] = fmaxf(fmaxf(s4[0][r], s4[1][r]), fmaxf(s4[2][r], s4[3][r]));
#pragma unroll
      for (int off = 8; off >= 1; off >>= 1)
#pragma unroll
        for (int r = 0; r < 4; ++r)
          mnew[r] = fmaxf(mnew[r], __shfl_xor(mnew[r], off));
#pragma unroll
      for (int r = 0; r < 4; ++r) {
        mnew[r] = fmaxf(mnew[r], m_i[r]);
        alpha[r] = __expf(m_i[r] - mnew[r]);
        m_i[r] = mnew[r];
      }
#pragma unroll
      for (int nt = 0; nt < 4; ++nt)
#pragma unroll
        for (int r = 0; r < 4; ++r)
          s4[nt][r] = __expf(s4[nt][r] - mnew[r]);
#pragma unroll
      for (int r = 0; r < 4; ++r)
        rs[r] = (s4[0][r] + s4[1][r]) + (s4[2][r] + s4[3][r]);
#pragma unroll
      for (int off = 8; off >= 1; off >>= 1)
#pragma unroll
        for (int r = 0; r < 4; ++r)
          rs[r] += __shfl_xor(rs[r], off);
#pragma unroll
      for (int r = 0; r < 4; ++r) l_i[r] = l_i[r] * alpha[r] + rs[r];
#pragma unroll
      for (int nt = 0; nt < 4; ++nt)
#pragma unroll
        for (int r = 0; r < 4; ++r) O[nt][r] *= alpha[r];
      // P: C-layout (row=quad*4+r, col=nt*16+l15) -> LDS
#pragma unroll
      for (int nt = 0; nt < 4; ++nt)
#pragma unroll
        for (int r = 0; r < 4; ++r)
          Ps[w][(quad * 4 + r) * 72 + nt * 16 + l15] = f2bf(s4[nt][r]);
    }
    __syncthreads();
    if (active) {
      short8 pf0 = *(const short8*)(&Ps[w][l15 * 72 + quad * 8]);       // A-layout
      short8 pf1 = *(const short8*)(&Ps[w][l15 * 72 + 32 + quad * 8]);
#pragma unroll
      for (int nt = 0; nt < 4; ++nt) {
        short8 vf0 = *(const short8*)(&Vs[(nt * 16 + l15) * 72 + quad * 8]);
        short8 vf1 = *(const short8*)(&Vs[(nt * 16 + l15) * 72 + 32 + quad * 8]);
        O[nt] = __builtin_amdgcn_mfma_f32_16x16x32_bf16(pf0, vf0, O[nt], 0, 0, 0);
        O[nt] = __builtin_amdgcn_mfma_f32_16x16x32_bf16(pf1, vf1, O[nt], 0, 0, 0);
      }
    }
    __syncthreads();
  }

  float inv[4];
#pragma unroll
  for (int r = 0; r < 4; ++r) inv[r] = 1.0f / l_i[r];
#pragma unroll
  for (int nt = 0; nt < 4; ++nt)
#pragma unroll
    for (int r = 0; r < 4; ++r) {
      const int t = rowbase + quad * 4 + r;
      ctx[(size_t)(b * T_SZ + t) * DM + h * 64 + nt * 16 + l15] = f2bf(O[nt][r] * inv[r]);
    }
}

// --------------------------------------------------
extern "C" void kernel_launch(void* const* d_in, const int* in_sizes, int n_in,
                              void* d_out, int out_size, void* d_ws, size_t ws_size,
                              hipStream_t stream) {
  const float* x  = (const float*)d_in[0];
  const float* Wq = (const float*)d_in[1];
  const float* Wk = (const float*)d_in[2];
  const float* Wv = (const float*)d_in[3];
  const float* Wo = (const float*)d_in[4];
  float* out = (float*)d_out;

  // workspace (bf16 elements): [xb | Wt(q,k,v,o transposed) | Q | K | V], ctx reuses xb
  short* ws  = (short*)d_ws;
  short* xb  = ws;                         //  8388608 el (16 MB)
  short* Wt  = ws + 8388608;               //  4*1048576 el (8 MB)
  short* QKV = Wt + 4 * 1048576;           //  3*8388608 el (48 MB)
  short* Qb  = QKV;
  short* Kb  = QKV + 8388608;
  short* Vb  = QKV + 2 * 8388608;
  short* ctx = xb;                         // x dead after QKV projection

  cvt_x_kernel<<<8192, 256, 0, stream>>>(x, xb);
  cvt_w_kernel<<<dim3(32, 32, 4), dim3(32, 8), 0, stream>>>(Wq, Wk, Wv, Wo, Wt);
  gemm_bt<0><<<dim3(64, 24), 256, 0, stream>>>(xb, Wt, QKV, nullptr, 1024);
  attn_kernel<<<dim3(32, 64), 256, 0, stream>>>(Qb, Kb, Vb, ctx);
  gemm_bt<1><<<dim3(64, 8), 256, 0, stream>>>(ctx, Wt + 3 * 1048576, nullptr, out, 1024);
}

// Round 2
// 317.229 us; speedup vs baseline: 1.5590x; 1.5590x over previous
//
#include <hip/hip_runtime.h>

// ---------------------------------------------------------------------------
// MHA: out = softmax_causal((xWq)(xWk)^T / sqrt(64)) (xWv) Wo
// B=4 T=2048 D=1024 H=16 Dh=64.  All matmuls in bf16 MFMA (fp32 accum).
// ---------------------------------------------------------------------------

typedef short  short8  __attribute__((ext_vector_type(8)));
typedef short  short4v __attribute__((ext_vector_type(4)));
typedef float  floatx4 __attribute__((ext_vector_type(4)));

#define T_SZ 2048
#define DM   1024

// 0.125 (Dh^-0.5) * log2(e): softmax done in base-2 domain -> native v_exp_f32
#define QSCALE 0.18033688011112042f

__device__ __forceinline__ short f2bf(float f) {
  unsigned u = __float_as_uint(f);
  u += 0x7fffu + ((u >> 16) & 1u);        // RNE
  return (short)(u >> 16);
}

__device__ __forceinline__ void gll16(const void* g, void* l) {
  __builtin_amdgcn_global_load_lds((const __attribute__((address_space(1))) void*)g,
                                   (__attribute__((address_space(3))) void*)l, 16, 0, 0);
}

// -------------------------------------------------- x fp32 -> bf16
__global__ void cvt_x_kernel(const float* __restrict__ x, short* __restrict__ xb) {
  const int i = (blockIdx.x * 256 + threadIdx.x) * 4;
  const float4 v = *(const float4*)(x + i);
  short4v o;
  o.x = f2bf(v.x); o.y = f2bf(v.y); o.z = f2bf(v.z); o.w = f2bf(v.w);
  *(short4v*)(xb + i) = o;
}

// -------------------------------------------------- W fp32 [K,N] -> bf16 W^T [N,K]
__global__ void cvt_w_kernel(const float* __restrict__ s0, const float* __restrict__ s1,
                             const float* __restrict__ s2, const float* __restrict__ s3,
                             short* __restrict__ dst) {
  const float* srcs[4] = {s0, s1, s2, s3};
  const float* src = srcs[blockIdx.z];
  short* d = dst + (size_t)blockIdx.z * 1048576;
  __shared__ float tile[32][33];
  const int tx = threadIdx.x, ty = threadIdx.y;       // block (32,8)
  const int n_base = blockIdx.x * 32, k_base = blockIdx.y * 32;
#pragma unroll
  for (int j = 0; j < 4; ++j)
    tile[ty + j * 8][tx] = src[(size_t)(k_base + ty + j * 8) * 1024 + n_base + tx];
  __syncthreads();
#pragma unroll
  for (int j = 0; j < 4; ++j)
    d[(size_t)(n_base + ty + j * 8) * 1024 + k_base + tx] = f2bf(tile[tx][ty + j * 8]);
}

// -------------------------------------------------- GEMM  C = A[M,K] * Bt[N,K]^T
// MODE 0: QKV epilogue -> bf16 [3][B*H][T][64], Q scaled by QSCALE
// MODE 1: fp32 row-major epilogue -> d_out
template <int MODE>
__global__ void gemm_bt(const short* __restrict__ A, const short* __restrict__ Bt,
                        short* __restrict__ obf, float* __restrict__ of, int K) {
  __shared__ short As[128 * 32];
  __shared__ short Bs[128 * 32];
  const int tid  = threadIdx.x;
  const int w    = tid >> 6, lane = tid & 63;
  const int quad = lane >> 4, l15 = lane & 15;
  const int wr   = w >> 1, wc = w & 1;
  const int m0   = blockIdx.x * 128;
  const int n0   = blockIdx.y * 128;
  const int arow = tid >> 2, apart = tid & 3;

  floatx4 acc[4][4] = {};

  for (int kk = 0; kk < K; kk += 32) {
    gll16(A  + (size_t)(m0 + arow) * K      + kk + apart * 8, &As[tid * 8]);
    gll16(A  + (size_t)(m0 + 64 + arow) * K + kk + apart * 8, &As[(256 + tid) * 8]);
    gll16(Bt + (size_t)(n0 + arow) * K      + kk + apart * 8, &Bs[tid * 8]);
    gll16(Bt + (size_t)(n0 + 64 + arow) * K + kk + apart * 8, &Bs[(256 + tid) * 8]);
    __syncthreads();
    short8 af[4], bf[4];
#pragma unroll
    for (int i = 0; i < 4; ++i)
      af[i] = *(const short8*)&As[(wr * 64 + i * 16 + l15) * 32 + quad * 8];
#pragma unroll
    for (int j = 0; j < 4; ++j)
      bf[j] = *(const short8*)&Bs[(wc * 64 + j * 16 + l15) * 32 + quad * 8];
#pragma unroll
    for (int i = 0; i < 4; ++i)
#pragma unroll
      for (int j = 0; j < 4; ++j)
        acc[i][j] = __builtin_amdgcn_mfma_f32_16x16x32_bf16(af[i], bf[j], acc[i][j], 0, 0, 0);
    __syncthreads();
  }

  if (MODE == 0) {
    const int wsel = n0 >> 10;
    const float scale = (wsel == 0) ? QSCALE : 1.0f;
    short* outw = obf + (size_t)wsel * (64u * 2048u * 64u);
    const int ncol0 = (n0 & 1023) + wc * 64;
#pragma unroll
    for (int i = 0; i < 4; ++i) {
      const int row0 = m0 + wr * 64 + i * 16 + quad * 4;
#pragma unroll
      for (int j = 0; j < 4; ++j) {
        const int col = ncol0 + j * 16 + l15;
        const int h = col >> 6, d = col & 63;
#pragma unroll
        for (int r = 0; r < 4; ++r) {
          const int rg = row0 + r;
          const int b = rg >> 11, t = rg & 2047;
          outw[(((size_t)(b * 16 + h) * 2048 + t) << 6) + d] = f2bf(acc[i][j][r] * scale);
        }
      }
    }
  } else {
#pragma unroll
    for (int i = 0; i < 4; ++i) {
      const int row0 = m0 + wr * 64 + i * 16 + quad * 4;
#pragma unroll
      for (int j = 0; j < 4; ++j) {
        const int col = n0 + wc * 64 + j * 16 + l15;
#pragma unroll
        for (int r = 0; r < 4; ++r)
          of[(size_t)(row0 + r) * 1024 + col] = acc[i][j][r];
      }
    }
  }
}

// -------------------------------------------------- V [bh][2048][64] -> Vt [bh][64][2048]
// one-shot transpose so attention can stage V^T with vectorized LDS writes
__global__ void vpose_kernel(const short* __restrict__ V, short* __restrict__ Vt) {
  __shared__ short t_[64 * 64];     // XOR-swizzled 64x64 tile
  const int bh = blockIdx.y;
  const int t0 = blockIdx.x * 64;
  const int tid = threadIdx.x;
  const short* src = V + ((size_t)bh * 2048 + t0) * 64;
  short* dst = Vt + (size_t)bh * (64 * 2048) + t0;
#pragma unroll
  for (int e = 0; e < 2; ++e) {
    const int idx = e * 256 + tid;
    const int tr = idx >> 3, c = idx & 7;
    const int cs = c ^ (tr & 7) ^ ((tr >> 3) & 7);
    *(short8*)&t_[tr * 64 + cs * 8] = *(const short8*)(src + tr * 64 + c * 8);
  }
  __syncthreads();
#pragma unroll
  for (int e = 0; e < 2; ++e) {
    const int idx = e * 256 + tid;
    const int dr = idx >> 3, p = idx & 7;
    short8 o;
#pragma unroll
    for (int j = 0; j < 8; ++j) {
      const int t = p * 8 + j;
      const int cs = (dr >> 3) ^ (t & 7) ^ ((t >> 3) & 7);
      o[j] = t_[t * 64 + cs * 8 + (dr & 7)];
    }
    *(short8*)(dst + dr * 2048 + p * 8) = o;
  }
}

// -------------------------------------------------- flash attention (causal)
// grid (8, B*H), block 512 (8 waves).  Each block processes q-tiles bx and
// 15-bx (work = 2bx+2 + 32-2bx = 34 tiles: perfectly balanced).  Wave w owns
// 16 q rows.  Q pre-scaled by 0.125*log2e; softmax in exp2 domain.
__global__ __launch_bounds__(512) void attn_kernel(
    const short* __restrict__ Qg, const short* __restrict__ Kg,
    const short* __restrict__ Vt, short* __restrict__ ctx) {
  __shared__ short Ks[64 * 72];     // [t_k][d], pad 72 (144B rows, 16B aligned)
  __shared__ short Vs[64 * 72];     // [d][t_k] (from pre-transposed V^T)
  __shared__ short Ps[8][16 * 72];  // per-wave P round-trip (C-layout -> A-layout)

  const int tid  = threadIdx.x;
  const int w    = tid >> 6, lane = tid & 63;
  const int quad = lane >> 4, l15 = lane & 15;
  const int bh = blockIdx.y;
  const int b  = bh >> 4, h = bh & 15;

  const size_t base = (size_t)bh * (T_SZ * 64);
  const short* Qb  = Qg + base;
  const short* Kb  = Kg + base;
  const short* Vtb = Vt + base;

  const int srow = tid >> 3, spart = tid & 7;   // staging: 512 thr = 64 rows x 8 parts

  for (int qsel = 0; qsel < 2; ++qsel) {
    const int qi = qsel ? (15 - (int)blockIdx.x) : (int)blockIdx.x;
    const int q0 = qi << 7;
    const int rowb = q0 + w * 16;

    const short8 qf0 = *(const short8*)(Qb + (size_t)(rowb + l15) * 64 + quad * 8);
    const short8 qf1 = *(const short8*)(Qb + (size_t)(rowb + l15) * 64 + 32 + quad * 8);

    floatx4 O[4] = {};
    float m_i[4], l_i[4];
#pragma unroll
    for (int r = 0; r < 4; ++r) { m_i[r] = -1e30f; l_i[r] = 0.0f; }

    const int ktiles = 2 * qi + 2;
    for (int kt = 0; kt < ktiles; ++kt) {
      const int k0 = kt << 6;
      *(short8*)&Ks[srow * 72 + spart * 8] =
          *(const short8*)(Kb + (size_t)(k0 + srow) * 64 + spart * 8);
      *(short8*)&Vs[srow * 72 + spart * 8] =
          *(const short8*)(Vtb + (size_t)srow * 2048 + k0 + spart * 8);
      __syncthreads();

      if (k0 <= rowb + 15) {
        floatx4 s4[4] = {};
#pragma unroll
        for (int nt = 0; nt < 4; ++nt) {
          const short8 kf0 = *(const short8*)(&Ks[(nt * 16 + l15) * 72 + quad * 8]);
          const short8 kf1 = *(const short8*)(&Ks[(nt * 16 + l15) * 72 + 32 + quad * 8]);
          s4[nt] = __builtin_amdgcn_mfma_f32_16x16x32_bf16(qf0, kf0, s4[nt], 0, 0, 0);
          s4[nt] = __builtin_amdgcn_mfma_f32_16x16x32_bf16(qf1, kf1, s4[nt], 0, 0, 0);
        }
        if (k0 + 63 > rowb) {                    // diagonal tile: element mask
#pragma unroll
          for (int nt = 0; nt < 4; ++nt) {
            const int col = k0 + nt * 16 + l15;
#pragma unroll
            for (int r = 0; r < 4; ++r)
              if (col > rowb + quad * 4 + r) s4[nt][r] = -1e30f;
          }
        }
        float mnew[4], alpha[4], rs[4];
#pragma unroll
        for (int r = 0; r < 4; ++r)
          mnew[r] = fmaxf(fmaxf(s4[0][r], s4[1][r]), fmaxf(s4[2][r], s4[3][r]));
#pragma unroll
        for (int off = 8; off >= 1; off >>= 1)
#pragma unroll
          for (int r = 0; r < 4; ++r)
            mnew[r] = fmaxf(mnew[r], __shfl_xor(mnew[r], off));
#pragma unroll
        for (int r = 0; r < 4; ++r) {
          mnew[r] = fmaxf(mnew[r], m_i[r]);
          alpha[r] = exp2f(m_i[r] - mnew[r]);
          m_i[r] = mnew[r];
        }
#pragma unroll
        for (int nt = 0; nt < 4; ++nt)
#pragma unroll
          for (int r = 0; r < 4; ++r)
            s4[nt][r] = exp2f(s4[nt][r] - mnew[r]);
#pragma unroll
        for (int r = 0; r < 4; ++r)
          rs[r] = (s4[0][r] + s4[1][r]) + (s4[2][r] + s4[3][r]);
#pragma unroll
        for (int off = 8; off >= 1; off >>= 1)
#pragma unroll
          for (int r = 0; r < 4; ++r)
            rs[r] += __shfl_xor(rs[r], off);
#pragma unroll
        for (int r = 0; r < 4; ++r) l_i[r] = l_i[r] * alpha[r] + rs[r];
#pragma unroll
        for (int nt = 0; nt < 4; ++nt)
#pragma unroll
          for (int r = 0; r < 4; ++r) O[nt][r] *= alpha[r];
        // P: C-layout (row=quad*4+r, col=nt*16+l15) -> per-wave LDS (no barrier)
#pragma unroll
        for (int nt = 0; nt < 4; ++nt)
#pragma unroll
          for (int r = 0; r < 4; ++r)
            Ps[w][(quad * 4 + r) * 72 + nt * 16 + l15] = f2bf(s4[nt][r]);
        const short8 pf0 = *(const short8*)(&Ps[w][l15 * 72 + quad * 8]);
        const short8 pf1 = *(const short8*)(&Ps[w][l15 * 72 + 32 + quad * 8]);
#pragma unroll
        for (int nt = 0; nt < 4; ++nt) {
          const short8 vf0 = *(const short8*)(&Vs[(nt * 16 + l15) * 72 + quad * 8]);
          const short8 vf1 = *(const short8*)(&Vs[(nt * 16 + l15) * 72 + 32 + quad * 8]);
          O[nt] = __builtin_amdgcn_mfma_f32_16x16x32_bf16(pf0, vf0, O[nt], 0, 0, 0);
          O[nt] = __builtin_amdgcn_mfma_f32_16x16x32_bf16(pf1, vf1, O[nt], 0, 0, 0);
        }
      }
      __syncthreads();
    }

    float inv[4];
#pragma unroll
    for (int r = 0; r < 4; ++r) inv[r] = 1.0f / l_i[r];
#pragma unroll
    for (int nt = 0; nt < 4; ++nt)
#pragma unroll
      for (int r = 0; r < 4; ++r) {
        const int t = rowb + quad * 4 + r;
        ctx[(size_t)(b * T_SZ + t) * DM + h * 64 + nt * 16 + l15] = f2bf(O[nt][r] * inv[r]);
      }
  }
}

// --------------------------------------------------
extern "C" void kernel_launch(void* const* d_in, const int* in_sizes, int n_in,
                              void* d_out, int out_size, void* d_ws, size_t ws_size,
                              hipStream_t stream) {
  const float* x  = (const float*)d_in[0];
  const float* Wq = (const float*)d_in[1];
  const float* Wk = (const float*)d_in[2];
  const float* Wv = (const float*)d_in[3];
  const float* Wo = (const float*)d_in[4];
  float* out = (float*)d_out;

  // bf16 workspace layout (region reuse keeps total at 75.5 MB):
  //   xb [8M]   : x bf16; dead after gemm<0>  -> reused as Vt
  //   Wt [4x1M] : transposed weights
  //   Q,K,Vn [8M each] : projections; Vn dead after vpose -> reused as ctx
  short* ws  = (short*)d_ws;
  short* xb  = ws;
  short* Wt  = ws + 8388608;
  short* Qb  = Wt + 4 * 1048576;
  short* Kb  = Qb + 8388608;
  short* Vn  = Kb + 8388608;
  short* Vt  = xb;                         // reuse
  short* ctx = Vn;                         // reuse

  cvt_x_kernel<<<8192, 256, 0, stream>>>(x, xb);
  cvt_w_kernel<<<dim3(32, 32, 4), dim3(32, 8), 0, stream>>>(Wq, Wk, Wv, Wo, Wt);
  gemm_bt<0><<<dim3(64, 24), 256, 0, stream>>>(xb, Wt, Qb /*==QKV base*/, nullptr, 1024);
  vpose_kernel<<<dim3(32, 64), 256, 0, stream>>>(Vn, Vt);
  attn_kernel<<<dim3(8, 64), 512, 0, stream>>>(Qb, Kb, Vt, ctx);
  gemm_bt<1><<<dim3(64, 8), 256, 0, stream>>>(ctx, Wt + 3 * 1048576, nullptr, out, 1024);
}

// Round 3
// 268.777 us; speedup vs baseline: 1.8401x; 1.1803x over previous
//
#include <hip/hip_runtime.h>

// ---------------------------------------------------------------------------
// MHA: out = softmax_causal((xWq)(xWk)^T / sqrt(64)) (xWv) Wo
// B=4 T=2048 D=1024 H=16 Dh=64.  All matmuls in bf16 MFMA (fp32 accum).
// Attention computed transposed (S^T = K Q^T, O^T = V^T P^T) so softmax
// stats are per-lane scalars and P packs to ds_write_b64.
// ---------------------------------------------------------------------------

typedef short  short8  __attribute__((ext_vector_type(8)));
typedef short  short4v __attribute__((ext_vector_type(4)));
typedef float  floatx4 __attribute__((ext_vector_type(4)));
typedef unsigned uint2v __attribute__((ext_vector_type(2)));

#define T_SZ 2048
#define DM   1024

// 0.125 (Dh^-0.5) * log2(e): softmax in base-2 domain -> native v_exp_f32
#define QSCALE 0.18033688011112042f

__device__ __forceinline__ short f2bf(float f) {
  unsigned u = __float_as_uint(f);
  u += 0x7fffu + ((u >> 16) & 1u);        // RNE
  return (short)(u >> 16);
}

// pack 2 floats -> bf16x2 dword (round-half-up), 3 VALU ops
__device__ __forceinline__ unsigned pack_bf(float lo, float hi) {
  return __builtin_amdgcn_perm(__float_as_uint(hi) + 0x8000u,
                               __float_as_uint(lo) + 0x8000u, 0x07060302u);
}

__device__ __forceinline__ void gll16(const void* g, void* l) {
  __builtin_amdgcn_global_load_lds((const __attribute__((address_space(1))) void*)g,
                                   (__attribute__((address_space(3))) void*)l, 16, 0, 0);
}

// -------------------------------------------------- x fp32 -> bf16
__global__ void cvt_x_kernel(const float* __restrict__ x, short* __restrict__ xb) {
  const int i = (blockIdx.x * 256 + threadIdx.x) * 4;
  const float4 v = *(const float4*)(x + i);
  short4v o;
  o.x = f2bf(v.x); o.y = f2bf(v.y); o.z = f2bf(v.z); o.w = f2bf(v.w);
  *(short4v*)(xb + i) = o;
}

// -------------------------------------------------- W fp32 [K,N] -> bf16 W^T [N,K]
__global__ void cvt_w_kernel(const float* __restrict__ s0, const float* __restrict__ s1,
                             const float* __restrict__ s2, const float* __restrict__ s3,
                             short* __restrict__ dst) {
  const float* srcs[4] = {s0, s1, s2, s3};
  const float* src = srcs[blockIdx.z];
  short* d = dst + (size_t)blockIdx.z * 1048576;
  __shared__ float tile[32][33];
  const int tx = threadIdx.x, ty = threadIdx.y;       // block (32,8)
  const int n_base = blockIdx.x * 32, k_base = blockIdx.y * 32;
#pragma unroll
  for (int j = 0; j < 4; ++j)
    tile[ty + j * 8][tx] = src[(size_t)(k_base + ty + j * 8) * 1024 + n_base + tx];
  __syncthreads();
#pragma unroll
  for (int j = 0; j < 4; ++j)
    d[(size_t)(n_base + ty + j * 8) * 1024 + k_base + tx] = f2bf(tile[tx][ty + j * 8]);
}

// -------------------------------------------------- GEMM  C = A[M,K] * Bt[N,K]^T
// MODE 0: QKV epilogue.  Q (wsel0, scaled) / K (wsel1) -> bf16 [bh][t][64];
//         V (wsel2) -> V^T bf16 [bh][64][t] (transpose fused, 8B packed stores)
// MODE 1: fp32 row-major epilogue -> d_out
template <int MODE>
__global__ void gemm_bt(const short* __restrict__ A, const short* __restrict__ Bt,
                        short* __restrict__ obf, short* __restrict__ vt,
                        float* __restrict__ of, int K) {
  __shared__ short As[128 * 32];
  __shared__ short Bs[128 * 32];
  const int tid  = threadIdx.x;
  const int w    = tid >> 6, lane = tid & 63;
  const int quad = lane >> 4, l15 = lane & 15;
  const int wr   = w >> 1, wc = w & 1;
  const int m0   = blockIdx.x * 128;
  const int n0   = blockIdx.y * 128;
  const int arow = tid >> 2, apart = tid & 3;

  floatx4 acc[4][4] = {};

  for (int kk = 0; kk < K; kk += 32) {
    gll16(A  + (size_t)(m0 + arow) * K      + kk + apart * 8, &As[tid * 8]);
    gll16(A  + (size_t)(m0 + 64 + arow) * K + kk + apart * 8, &As[(256 + tid) * 8]);
    gll16(Bt + (size_t)(n0 + arow) * K      + kk + apart * 8, &Bs[tid * 8]);
    gll16(Bt + (size_t)(n0 + 64 + arow) * K + kk + apart * 8, &Bs[(256 + tid) * 8]);
    __syncthreads();
    short8 af[4], bf[4];
#pragma unroll
    for (int i = 0; i < 4; ++i)
      af[i] = *(const short8*)&As[(wr * 64 + i * 16 + l15) * 32 + quad * 8];
#pragma unroll
    for (int j = 0; j < 4; ++j)
      bf[j] = *(const short8*)&Bs[(wc * 64 + j * 16 + l15) * 32 + quad * 8];
#pragma unroll
    for (int i = 0; i < 4; ++i)
#pragma unroll
      for (int j = 0; j < 4; ++j)
        acc[i][j] = __builtin_amdgcn_mfma_f32_16x16x32_bf16(af[i], bf[j], acc[i][j], 0, 0, 0);
    __syncthreads();
  }

  if (MODE == 0) {
    const int wsel = n0 >> 10;
    const int ncol0 = (n0 & 1023) + wc * 64;
    if (wsel < 2) {
      const float scale = (wsel == 0) ? QSCALE : 1.0f;
      short* outw = obf + (size_t)wsel * (64u * 2048u * 64u);
#pragma unroll
      for (int i = 0; i < 4; ++i) {
        const int row0 = m0 + wr * 64 + i * 16 + quad * 4;
#pragma unroll
        for (int j = 0; j < 4; ++j) {
          const int col = ncol0 + j * 16 + l15;
          const int h = col >> 6, d = col & 63;
#pragma unroll
          for (int r = 0; r < 4; ++r) {
            const int rg = row0 + r;
            const int b = rg >> 11, t = rg & 2047;
            outw[(((size_t)(b * 16 + h) * 2048 + t) << 6) + d] = f2bf(acc[i][j][r] * scale);
          }
        }
      }
    } else {                         // V -> V^T [bh][d][2048], 4 consecutive t per lane
#pragma unroll
      for (int i = 0; i < 4; ++i) {
        const int row0 = m0 + wr * 64 + i * 16 + quad * 4;   // t base (mult of 4)
        const int b = row0 >> 11, t = row0 & 2047;
#pragma unroll
        for (int j = 0; j < 4; ++j) {
          const int col = ncol0 + j * 16 + l15;
          const int h = col >> 6, d = col & 63;
          short4v pv;
#pragma unroll
          for (int r = 0; r < 4; ++r) pv[r] = f2bf(acc[i][j][r]);
          *(short4v*)(vt + (((size_t)(b * 16 + h) * 64 + d) << 11) + t) = pv;
        }
      }
    }
  } else {
#pragma unroll
    for (int i = 0; i < 4; ++i) {
      const int row0 = m0 + wr * 64 + i * 16 + quad * 4;
#pragma unroll
      for (int j = 0; j < 4; ++j) {
        const int col = n0 + wc * 64 + j * 16 + l15;
#pragma unroll
        for (int r = 0; r < 4; ++r)
          of[(size_t)(row0 + r) * 1024 + col] = acc[i][j][r];
      }
    }
  }
}

// -------------------------------------------------- flash attention (causal, transposed)
// grid (8, B*H), block 512 (8 waves).  Block does q-tiles bx and 15-bx
// (128 q rows each; k-iterations (bx+1)+(16-bx)=17: balanced).  Wave w owns
// q rows [q0+16w, q0+16w+16), one lane per q (q = rowb + (lane&15)).
// BN=128 k-cols per iteration.  Q pre-scaled by 0.125*log2e.
__global__ __launch_bounds__(512, 4) void attn_kernel(
    const short* __restrict__ Qg, const short* __restrict__ Kg,
    const short* __restrict__ Vt, short* __restrict__ ctx) {
  __shared__ short Ks[128 * 72];       // [t_k][d]   (18.0 KB)
  __shared__ short Vs[64 * 136];       // [d][t_k]   (17.0 KB)
  __shared__ short Ps[8 * 16 * 136];   // per-wave [q][t_k]  (34.0 KB)

  const int tid  = threadIdx.x;
  const int w    = tid >> 6, lane = tid & 63;
  const int quad = lane >> 4, l15 = lane & 15;
  const int bh = blockIdx.y;
  const int b  = bh >> 4, h = bh & 15;

  const size_t base = (size_t)bh * (T_SZ * 64);
  const short* Qb  = Qg + base;
  const short* Kb  = Kg + base;
  const short* Vtb = Vt + base;
  short* Pw = &Ps[w * (16 * 136)];

  const int kr = tid >> 3, kp = tid & 7;     // K staging: rows kr, kr+64
  const int vr = tid >> 4, vp = tid & 15;    // V staging: rows vr, vr+32

  for (int qsel = 0; qsel < 2; ++qsel) {
    const int qi = qsel ? (15 - (int)blockIdx.x) : (int)blockIdx.x;
    const int q0 = qi << 7;
    const int rowb = q0 + w * 16;

    const short8 qf0 = *(const short8*)(Qb + (size_t)(rowb + l15) * 64 + quad * 8);
    const short8 qf1 = *(const short8*)(Qb + (size_t)(rowb + l15) * 64 + 32 + quad * 8);

    floatx4 O[4] = {};
    float m_i = -1e30f, l_i = 0.0f;

    const int ktiles = qi + 1;
    // preload tile 0 into registers
    short8 kA = *(const short8*)(Kb + (size_t)kr * 64 + kp * 8);
    short8 kB = *(const short8*)(Kb + (size_t)(kr + 64) * 64 + kp * 8);
    short8 vA = *(const short8*)(Vtb + (size_t)vr * 2048 + vp * 8);
    short8 vB = *(const short8*)(Vtb + (size_t)(vr + 32) * 2048 + vp * 8);

    for (int kt = 0; kt < ktiles; ++kt) {
      const int k0 = kt << 7;
      __syncthreads();                       // prior tile's LDS reads done
      *(short8*)&Ks[kr * 72 + kp * 8] = kA;
      *(short8*)&Ks[(kr + 64) * 72 + kp * 8] = kB;
      *(short8*)&Vs[vr * 136 + vp * 8] = vA;
      *(short8*)&Vs[(vr + 32) * 136 + vp * 8] = vB;
      if (kt + 1 < ktiles) {                 // prefetch next tile (hidden by compute)
        const int kn = (kt + 1) << 7;
        kA = *(const short8*)(Kb + (size_t)(kn + kr) * 64 + kp * 8);
        kB = *(const short8*)(Kb + (size_t)(kn + kr + 64) * 64 + kp * 8);
        vA = *(const short8*)(Vtb + (size_t)vr * 2048 + kn + vp * 8);
        vB = *(const short8*)(Vtb + (size_t)(vr + 32) * 2048 + kn + vp * 8);
      }
      __syncthreads();                       // staged LDS visible

      const int dk  = rowb - k0;             // >= 0
      const int lim = dk + l15;              // q index relative to k0, per lane
      floatx4 s4[8];
      float tmax = -1e30f;
#pragma unroll
      for (int mt = 0; mt < 8; ++mt) {
        if (mt * 16 < dk + 16) {             // m-tile not fully masked (wave-uniform)
          const short8 kf0 = *(const short8*)&Ks[(mt * 16 + l15) * 72 + quad * 8];
          const short8 kf1 = *(const short8*)&Ks[(mt * 16 + l15) * 72 + 32 + quad * 8];
          floatx4 s = {};
          s = __builtin_amdgcn_mfma_f32_16x16x32_bf16(kf0, qf0, s, 0, 0, 0);
          s = __builtin_amdgcn_mfma_f32_16x16x32_bf16(kf1, qf1, s, 0, 0, 0);
          if (mt * 16 + 15 > dk) {           // diagonal m-tile: element mask
#pragma unroll
            for (int r = 0; r < 4; ++r)
              if (mt * 16 + quad * 4 + r > lim) s[r] = -1e30f;
          }
          s4[mt] = s;
          tmax = fmaxf(tmax, fmaxf(fmaxf(s[0], s[1]), fmaxf(s[2], s[3])));
        }
      }
      tmax = fmaxf(tmax, __shfl_xor(tmax, 16));
      tmax = fmaxf(tmax, __shfl_xor(tmax, 32));
      const float mnew  = fmaxf(m_i, tmax);
      const float alpha = exp2f(m_i - mnew);
      m_i = mnew;

      float rs = 0.0f;
#pragma unroll
      for (int mt = 0; mt < 8; ++mt) {
        const int paddr = l15 * 136 + mt * 16 + quad * 4;    // 8B aligned
        if (mt * 16 < dk + 16) {
          floatx4 s = s4[mt];
#pragma unroll
          for (int r = 0; r < 4; ++r) s[r] = exp2f(s[r] - mnew);
          rs += (s[0] + s[1]) + (s[2] + s[3]);
          uint2v pd;
          pd.x = pack_bf(s[0], s[1]);
          pd.y = pack_bf(s[2], s[3]);
          *(uint2v*)&Pw[paddr] = pd;                         // ds_write_b64
        } else {
          uint2v z; z.x = 0; z.y = 0;
          *(uint2v*)&Pw[paddr] = z;
        }
      }
      rs += __shfl_xor(rs, 16);
      rs += __shfl_xor(rs, 32);
      l_i = l_i * alpha + rs;
#pragma unroll
      for (int dt = 0; dt < 4; ++dt)
#pragma unroll
        for (int r = 0; r < 4; ++r) O[dt][r] *= alpha;

      const int nact = min(8, ((dk + 15) >> 4) + 1);
      const int nch  = (nact + 1) >> 1;      // active K=32 chunks for PV
#pragma unroll
      for (int c = 0; c < 4; ++c) {
        if (c < nch) {
          const short8 pf = *(const short8*)&Pw[l15 * 136 + c * 32 + quad * 8];
#pragma unroll
          for (int dt = 0; dt < 4; ++dt) {
            const short8 vf = *(const short8*)&Vs[(dt * 16 + l15) * 136 + c * 32 + quad * 8];
            O[dt] = __builtin_amdgcn_mfma_f32_16x16x32_bf16(vf, pf, O[dt], 0, 0, 0);
          }
        }
      }
    }

    const float inv = 1.0f / l_i;
    const int t = rowb + l15;
    short* cb = ctx + (((size_t)(b * T_SZ + t)) << 10) + h * 64 + quad * 4;
#pragma unroll
    for (int dt = 0; dt < 4; ++dt) {
      short4v o4;
#pragma unroll
      for (int r = 0; r < 4; ++r) o4[r] = f2bf(O[dt][r] * inv);
      *(short4v*)(cb + dt * 16) = o4;        // 8B store, d = 16dt+quad*4..+3
    }
  }
}

// --------------------------------------------------
extern "C" void kernel_launch(void* const* d_in, const int* in_sizes, int n_in,
                              void* d_out, int out_size, void* d_ws, size_t ws_size,
                              hipStream_t stream) {
  const float* x  = (const float*)d_in[0];
  const float* Wq = (const float*)d_in[1];
  const float* Wk = (const float*)d_in[2];
  const float* Wv = (const float*)d_in[3];
  const float* Wo = (const float*)d_in[4];
  float* out = (float*)d_out;

  // bf16 workspace (72 MB):
  //   xb [8M]  : x bf16; dead after gemm<0> -> reused as ctx
  //   Wt [4x1M]: transposed weights
  //   Qb,Kb [8M each] : projections [bh][t][64]
  //   Vt [8M]  : V^T [bh][64][t]  (written directly by gemm<0> epilogue)
  short* ws  = (short*)d_ws;
  short* xb  = ws;
  short* Wt  = ws + 8388608;
  short* Qb  = Wt + 4 * 1048576;
  short* Kb  = Qb + 8388608;
  short* Vt  = Kb + 8388608;
  short* ctx = xb;

  cvt_x_kernel<<<8192, 256, 0, stream>>>(x, xb);
  cvt_w_kernel<<<dim3(32, 32, 4), dim3(32, 8), 0, stream>>>(Wq, Wk, Wv, Wo, Wt);
  gemm_bt<0><<<dim3(64, 24), 256, 0, stream>>>(xb, Wt, Qb, Vt, nullptr, 1024);
  attn_kernel<<<dim3(8, 64), 512, 0, stream>>>(Qb, Kb, Vt, ctx);
  gemm_bt<1><<<dim3(64, 8), 256, 0, stream>>>(ctx, Wt + 3 * 1048576, nullptr, nullptr, out, 1024);
}